// Round 1
// baseline (32.200 us; speedup 1.0000x reference)
//
#include <hip/hip_runtime.h>

// Problem constants
#define NBATCH 8
#define HH 512
#define WW 512
#define NPIX (HH * WW)              // 262144
#define IMG_ELEMS (NBATCH * 3 * NPIX)  // 6291456 floats per stitched output
#define OFF_ALBEDO 0
#define OFF_NORMAL ((size_t)IMG_ELEMS)
#define OFF_SHADING ((size_t)(2 * IMG_ELEMS))
#define OFF_LIGHT ((size_t)(3 * IMG_ELEMS))
#define N_LIGHT (NBATCH * 27 * 49)     // 10584
#define OFF_LOSS (OFF_LIGHT + N_LIGHT)
// tile-sum table: T[n][c][ti][tj], n=8, c=6, ti,tj=8 -> 3072 floats
#define T_ELEMS (NBATCH * 6 * 8 * 8)

__device__ __forceinline__ float fast_tanh(float x) {
    // tanh(x) = 1 - 2/(exp(2x)+1); saturates correctly at +/-inf of exp
    float e = __expf(2.0f * x);
    return 1.0f - 2.0f / (e + 1.0f);
}

// One block = 256 threads = one 16-row x 64-col chunk of a 64x64 tile.
// grid = N * 8(ti) * 8(tj) * 4(row-chunk) = 2048 blocks.
__global__ __launch_bounds__(256) void fused_heads_kernel(
    const float* __restrict__ inT, const float* __restrict__ inN,
    const float* __restrict__ Wa, const float* __restrict__ ba,
    const float* __restrict__ Wn, const float* __restrict__ bn,
    const float* __restrict__ Ws, const float* __restrict__ bs,
    float* __restrict__ out, float* __restrict__ T) {
    int bid = blockIdx.x;
    int n = bid >> 8;          // / 256
    int rem = bid & 255;
    int ti = rem >> 5;         // / 32
    int rem2 = rem & 31;
    int tj = rem2 >> 2;
    int rc = rem2 & 3;

    int t = threadIdx.x;
    int rowc = t >> 4;         // 0..15
    int col4 = t & 15;         // 0..15
    int y = ti * 64 + rc * 16 + rowc;
    int x = tj * 64 + col4 * 4;

    // Load 6 feature channels (3 from inputTensor, 3 from inputNorm), float4
    float4 f[6];
    size_t base = ((size_t)(n * 3) * HH + y) * WW + x;
#pragma unroll
    for (int c = 0; c < 3; ++c) {
        f[c]     = *reinterpret_cast<const float4*>(inT + base + (size_t)c * NPIX);
        f[c + 3] = *reinterpret_cast<const float4*>(inN + base + (size_t)c * NPIX);
    }

    // Three heads: out[n,o,y,x] = tanh(W[o,:].feat + b[o])  (stitch weights sum to 1)
    size_t obase = ((size_t)(n * 3) * HH + y) * WW + x;
#pragma unroll
    for (int h = 0; h < 3; ++h) {
        const float* W = (h == 0) ? Wa : (h == 1) ? Wn : Ws;
        const float* b = (h == 0) ? ba : (h == 1) ? bn : bs;
        float* o_ptr = out + ((h == 0) ? OFF_ALBEDO : (h == 1) ? OFF_NORMAL : OFF_SHADING);
#pragma unroll
        for (int o = 0; o < 3; ++o) {
            float bv = b[o];
            float ax = bv, ay = bv, az = bv, aw = bv;
#pragma unroll
            for (int c = 0; c < 6; ++c) {
                float w = W[o * 6 + c];
                ax = fmaf(w, f[c].x, ax);
                ay = fmaf(w, f[c].y, ay);
                az = fmaf(w, f[c].z, az);
                aw = fmaf(w, f[c].w, aw);
            }
            float4 r;
            r.x = fast_tanh(ax);
            r.y = fast_tanh(ay);
            r.z = fast_tanh(az);
            r.w = fast_tanh(aw);
            *reinterpret_cast<float4*>(o_ptr + obase + (size_t)o * NPIX) = r;
        }
    }

    // Per-channel partial sums for the 64x64 tile (for lighting's pooled means)
    float s[6];
#pragma unroll
    for (int c = 0; c < 6; ++c) s[c] = f[c].x + f[c].y + f[c].z + f[c].w;

    // wave (64-lane) butterfly reduce
#pragma unroll
    for (int off = 32; off > 0; off >>= 1) {
#pragma unroll
        for (int c = 0; c < 6; ++c) s[c] += __shfl_down(s[c], off, 64);
    }

    __shared__ float red[4][6];
    int wave = t >> 6;
    int lane = t & 63;
    if (lane == 0) {
#pragma unroll
        for (int c = 0; c < 6; ++c) red[wave][c] = s[c];
    }
    __syncthreads();
    if (t < 6) {
        float v = red[0][t] + red[1][t] + red[2][t] + red[3][t];
        atomicAdd(&T[((n * 6 + t) * 8 + ti) * 8 + tj], v);
    }
}

// lighting: for each (n,o,i,j): pooled over 128x128 patch = sum of 4 tile sums / 16384
__global__ __launch_bounds__(256) void lighting_kernel(
    const float* __restrict__ T, const float* __restrict__ Wl,
    const float* __restrict__ bl, float* __restrict__ out) {
    int tid = blockIdx.x * blockDim.x + threadIdx.x;
    if (tid > N_LIGHT) return;
    if (tid == N_LIGHT) {
        out[OFF_LOSS] = 0.0f;  // overlap_loss is identically zero
        return;
    }
    int n = tid / (27 * 49);
    int r = tid % (27 * 49);
    int o = r / 49;
    int r2 = r % 49;
    int i = r2 / 7;
    int j = r2 % 7;
    float acc = bl[o];
#pragma unroll
    for (int c = 0; c < 6; ++c) {
        const float* Tc = T + (size_t)((n * 6 + c) * 8) * 8;
        float p = Tc[i * 8 + j] + Tc[(i + 1) * 8 + j] + Tc[i * 8 + j + 1] +
                  Tc[(i + 1) * 8 + j + 1];
        acc = fmaf(Wl[o * 6 + c], p * (1.0f / 16384.0f), acc);
    }
    out[OFF_LIGHT + tid] = acc;
}

extern "C" void kernel_launch(void* const* d_in, const int* in_sizes, int n_in,
                              void* d_out, int out_size, void* d_ws, size_t ws_size,
                              hipStream_t stream) {
    const float* inT = (const float*)d_in[0];
    const float* inN = (const float*)d_in[1];
    const float* Wa = (const float*)d_in[2];
    const float* ba = (const float*)d_in[3];
    const float* Wn = (const float*)d_in[4];
    const float* bn = (const float*)d_in[5];
    const float* Ws = (const float*)d_in[6];
    const float* bs = (const float*)d_in[7];
    const float* Wl = (const float*)d_in[8];
    const float* bl = (const float*)d_in[9];
    float* out = (float*)d_out;
    float* T = (float*)d_ws;

    // zero the tile-sum table (we atomicAdd into it every call)
    hipMemsetAsync(d_ws, 0, T_ELEMS * sizeof(float), stream);

    fused_heads_kernel<<<NBATCH * 8 * 8 * 4, 256, 0, stream>>>(
        inT, inN, Wa, ba, Wn, bn, Ws, bs, out, T);

    lighting_kernel<<<(N_LIGHT + 1 + 255) / 256, 256, 0, stream>>>(T, Wl, bl, out);
}

// Round 2
// 30.114 us; speedup vs baseline: 1.0693x; 1.0693x over previous
//
#include <hip/hip_runtime.h>

// Problem constants
#define NBATCH 8
#define HH 512
#define WW 512
#define NPIX (HH * WW)                 // 262144
#define IMG_ELEMS (NBATCH * 3 * NPIX)  // 6291456 floats per stitched output
#define OFF_ALBEDO 0
#define OFF_NORMAL ((size_t)IMG_ELEMS)
#define OFF_SHADING ((size_t)(2 * IMG_ELEMS))
#define OFF_LIGHT ((size_t)(3 * IMG_ELEMS))
#define N_LIGHT (NBATCH * 27 * 49)     // 10584
#define OFF_LOSS (OFF_LIGHT + N_LIGHT)
#define NBLK (NBATCH * 8 * 8 * 4)      // 2048 blocks
// Partial-sum table: P[bid][c], c padded to 8 -> 2048*8 floats = 64 KB in d_ws.
// Every slot is written every call by exactly one block -> no zeroing, no atomics.

__device__ __forceinline__ float fast_tanh(float x) {
    // tanh(x) = 1 - 2/(exp(2x)+1); saturates correctly at +/-inf of exp
    float e = __expf(2.0f * x);
    return 1.0f - 2.0f / (e + 1.0f);
}

// One block = 256 threads = one 16-row x 64-col chunk of a 64x64 tile.
// grid = N * 8(ti) * 8(tj) * 4(row-chunk) = 2048 blocks.
__global__ __launch_bounds__(256) void fused_heads_kernel(
    const float* __restrict__ inT, const float* __restrict__ inN,
    const float* __restrict__ Wa, const float* __restrict__ ba,
    const float* __restrict__ Wn, const float* __restrict__ bn,
    const float* __restrict__ Ws, const float* __restrict__ bs,
    float* __restrict__ out, float* __restrict__ P) {
    int bid = blockIdx.x;
    int n = bid >> 8;          // / 256
    int rem = bid & 255;
    int ti = rem >> 5;         // / 32
    int rem2 = rem & 31;
    int tj = rem2 >> 2;
    int rc = rem2 & 3;

    int t = threadIdx.x;
    int rowc = t >> 4;         // 0..15
    int col4 = t & 15;         // 0..15
    int y = ti * 64 + rc * 16 + rowc;
    int x = tj * 64 + col4 * 4;

    // Load 6 feature channels (3 from inputTensor, 3 from inputNorm), float4
    float4 f[6];
    size_t base = ((size_t)(n * 3) * HH + y) * WW + x;
#pragma unroll
    for (int c = 0; c < 3; ++c) {
        f[c]     = *reinterpret_cast<const float4*>(inT + base + (size_t)c * NPIX);
        f[c + 3] = *reinterpret_cast<const float4*>(inN + base + (size_t)c * NPIX);
    }

    // Three heads: out[n,o,y,x] = tanh(W[o,:].feat + b[o])
    // (stitch weights are separable and sum to 1 at every pixel -> stitch == identity,
    //  and overlap_loss is identically zero since overlapping patches see the same pixels)
    size_t obase = ((size_t)(n * 3) * HH + y) * WW + x;
#pragma unroll
    for (int h = 0; h < 3; ++h) {
        const float* W = (h == 0) ? Wa : (h == 1) ? Wn : Ws;
        const float* b = (h == 0) ? ba : (h == 1) ? bn : bs;
        float* o_ptr = out + ((h == 0) ? OFF_ALBEDO : (h == 1) ? OFF_NORMAL : OFF_SHADING);
#pragma unroll
        for (int o = 0; o < 3; ++o) {
            float bv = b[o];
            float ax = bv, ay = bv, az = bv, aw = bv;
#pragma unroll
            for (int c = 0; c < 6; ++c) {
                float w = W[o * 6 + c];
                ax = fmaf(w, f[c].x, ax);
                ay = fmaf(w, f[c].y, ay);
                az = fmaf(w, f[c].z, az);
                aw = fmaf(w, f[c].w, aw);
            }
            float4 r;
            r.x = fast_tanh(ax);
            r.y = fast_tanh(ay);
            r.z = fast_tanh(az);
            r.w = fast_tanh(aw);
            *reinterpret_cast<float4*>(o_ptr + obase + (size_t)o * NPIX) = r;
        }
    }

    // Per-channel partial sums of this block's 16x64 chunk (for lighting's pooled means)
    float s[6];
#pragma unroll
    for (int c = 0; c < 6; ++c) s[c] = f[c].x + f[c].y + f[c].z + f[c].w;

    // wave (64-lane) butterfly reduce
#pragma unroll
    for (int off = 32; off > 0; off >>= 1) {
#pragma unroll
        for (int c = 0; c < 6; ++c) s[c] += __shfl_down(s[c], off, 64);
    }

    __shared__ float red[4][6];
    int wave = t >> 6;
    int lane = t & 63;
    if (lane == 0) {
#pragma unroll
        for (int c = 0; c < 6; ++c) red[wave][c] = s[c];
    }
    __syncthreads();
    if (t < 6) {
        float v = red[0][t] + red[1][t] + red[2][t] + red[3][t];
        P[(size_t)bid * 8 + t] = v;   // deterministic slot, no atomics, no memset
    }
}

// lighting: pooled mean over each 128x128 patch = sum of 16 block partials / 16384
__global__ __launch_bounds__(256) void lighting_kernel(
    const float* __restrict__ P, const float* __restrict__ Wl,
    const float* __restrict__ bl, float* __restrict__ out) {
    int tid = blockIdx.x * blockDim.x + threadIdx.x;
    if (tid > N_LIGHT) return;
    if (tid == N_LIGHT) {
        out[OFF_LOSS] = 0.0f;  // overlap_loss is identically zero
        return;
    }
    int n = tid / (27 * 49);
    int r = tid % (27 * 49);
    int o = r / 49;
    int r2 = r % 49;
    int i = r2 / 7;
    int j = r2 % 7;

    float s[6] = {0.f, 0.f, 0.f, 0.f, 0.f, 0.f};
#pragma unroll
    for (int di = 0; di < 2; ++di) {
#pragma unroll
        for (int dj = 0; dj < 2; ++dj) {
            int ti = i + di;
            int tj = j + dj;
            int bbase = ((n * 8 + ti) * 8 + tj) * 4;
#pragma unroll
            for (int rc = 0; rc < 4; ++rc) {
                const float* p = P + (size_t)(bbase + rc) * 8;
#pragma unroll
                for (int c = 0; c < 6; ++c) s[c] += p[c];
            }
        }
    }
    float acc = bl[o];
#pragma unroll
    for (int c = 0; c < 6; ++c)
        acc = fmaf(Wl[o * 6 + c], s[c] * (1.0f / 16384.0f), acc);
    out[OFF_LIGHT + tid] = acc;
}

extern "C" void kernel_launch(void* const* d_in, const int* in_sizes, int n_in,
                              void* d_out, int out_size, void* d_ws, size_t ws_size,
                              hipStream_t stream) {
    const float* inT = (const float*)d_in[0];
    const float* inN = (const float*)d_in[1];
    const float* Wa = (const float*)d_in[2];
    const float* ba = (const float*)d_in[3];
    const float* Wn = (const float*)d_in[4];
    const float* bn = (const float*)d_in[5];
    const float* Ws = (const float*)d_in[6];
    const float* bs = (const float*)d_in[7];
    const float* Wl = (const float*)d_in[8];
    const float* bl = (const float*)d_in[9];
    float* out = (float*)d_out;
    float* P = (float*)d_ws;

    fused_heads_kernel<<<NBLK, 256, 0, stream>>>(
        inT, inN, Wa, ba, Wn, bn, Ws, bs, out, P);

    lighting_kernel<<<(N_LIGHT + 1 + 255) / 256, 256, 0, stream>>>(P, Wl, bl, out);
}